// Round 12
// baseline (339.403 us; speedup 1.0000x reference)
//
#include <hip/hip_runtime.h>

#define RAD 6
#define KS 13
#define DIM 192
#define CH 3
#define W4C 48                  // float4 per row
#define PLANE4 (DIM * W4C)      // f4 per d-plane
#define VOL4 (DIM * PLANE4)     // f4 per channel
#define TOTAL (CH * DIM * DIM * DIM)

// ---------------- wave-autonomous geometry ----------------
#define WCH 2                   // f4 cols per wave
#define HTW 32                  // output h-rows per wave
#define WR (HTW + 2 * RAD)      // 44 W rows (incl. h-halo)
#define NHTW (DIM / HTW)        // 6
#define NWT (W4C / WCH)         // 24
#define DT 16                   // output depths per wave
#define NDT (DIM / DT)          // 12
#define NSTEP (DT + 2 * RAD)    // 28 planes streamed
#define WPB 2                   // waves per block
#define NTF (WPB * 64)          // 128 threads
#define TOTW (CH * NWT * NHTW * NDT)   // 5184 waves
#define GRIDF (TOTW / WPB)      // 2592 blocks = 8 * 324

// Extract 1D gaussian: g3[i][j][k] = g1[i]*g1[j]*g1[k], sum(g1)=1 -> row-sum recovers g1.
__global__ void g1_extract_kernel(const float* __restrict__ w, float* __restrict__ g1) {
    int i = threadIdx.x;
    if (i < KS) {
        float s = 0.f;
        for (int j = 0; j < KS * KS; ++j) s += w[i * KS * KS + j];
        g1[i] = s;
    }
}

// ---------------------------------------------------------------------------
// BARRIER-FREE wave-autonomous conv: wave = (c, 32 h-rows, 2 f4-cols, 16 d).
// v2 FIX (r11 absmax 0.92): cross-lane LDS RAW needs a WAVE-level fence --
// per-thread memory semantics let the compiler reorder the H-phase ds_reads
// above the W-phase ds_writes (different per-lane addresses), and the DS
// writes must drain (lgkmcnt(0)) before other lanes' data is read. Fence =
// asm "s_waitcnt lgkmcnt(0)" + "memory" clobber + sched_barrier(0)
// (rule #18). Still NO s_barrier: waves stay autonomous, no block convoy.
//   W: each lane loads its own 5-f4 w-window DIRECT from global (L1/L2
//      absorbs halo redundancy), 13-tap conv -> wave-private LDS strip.
//   H: 13 taps from own strip (after wave fence).
//   D: 14-deep register window, pair-stepped; plain store.
// 5184 free-running waves mix phases across all pipes.
// ---------------------------------------------------------------------------
__global__ __launch_bounds__(NTF, 4) void conv3d_fused(const float* __restrict__ in,
                                                       float* __restrict__ out,
                                                       const float* __restrict__ g1v) {
    __shared__ float4 wcb[WPB * WR * WCH];   // 176 f4 = 2816 B

    int bid = blockIdx.x;
    // bijective XCD swizzle: 2592 = 8 * 324
    bid = (bid & 7) * (GRIDF / 8) + (bid >> 3);
    const int widx = threadIdx.x >> 6;
    const int l = threadIdx.x & 63;

    int gw = bid * WPB + widx;              // adjacent waves share w-halo
    const int wt = gw % NWT;  gw /= NWT;
    const int ht = gw % NHTW; gw /= NHTW;
    const int dtt = gw % NDT; gw /= NDT;
    const int c  = gw;                       // 0..2
    const int h0 = ht * HTW;
    const int d0 = dtt * DT;

    const int r  = l >> 1;                   // 0..31 output row
    const int cw = l & 1;                    // 0..1 output col

    float g[KS];
#pragma unroll
    for (int k = 0; k < KS; ++k) g[k] = g1v[k];

    const float4* __restrict__ in4 = (const float4*)in;
    float4* __restrict__ out4 = (float4*)out;
    const float4 z4 = make_float4(0.f, 0.f, 0.f, 0.f);

    // ---- W tasks: task0 wo=l (W rows 0..31), task1 wo=64+l (rows 32..43, l<24)
    int off0[5], off1[5];
    float m0[5], m1[5];
    const bool t1act = (l < 24);
#pragma unroll
    for (int task = 0; task < 2; ++task) {
        const int wo = task * 64 + l;
        const int wr = wo >> 1, wc = wo & 1;
        const int grow = h0 - RAD + wr;
        const float rm = (grow >= 0 && grow < DIM) ? 1.f : 0.f;   // h zero-pad
        const int growc = min(max(grow, 0), DIM - 1);
#pragma unroll
        for (int j = 0; j < 5; ++j) {
            const int col = wt * WCH + wc - 2 + j;
            const int colc = min(max(col, 0), W4C - 1);
            const int o = c * VOL4 + growc * W4C + colc;          // + dp*PLANE4
            const float m = ((col >= 0 && col < W4C) ? 1.f : 0.f) * rm;
            if (task == 0) { off0[j] = o; m0[j] = m; }
            else           { off1[j] = o; m1[j] = m; }
        }
    }
    const int wbase = widx * (WR * WCH);     // wave-private strip base (f4)
    const int outB  = c * VOL4 + (h0 + r) * W4C + wt * WCH + cw;

    float4 wd[14];
#pragma unroll
    for (int j = 0; j < 14; ++j) wd[j] = z4;

#define STEPX(S, OFF)                                                             \
    {                                                                             \
        const int s_ = (S);                                                       \
        const int dp_ = d0 - RAD + s_;                                            \
        const bool dpv_ = (dp_ >= 0) && (dp_ < DIM);   /* wave-uniform */         \
        if (dpv_) {                                                               \
            const int pb_ = dp_ * PLANE4;                                         \
            float F[20];                                                          \
            _Pragma("unroll")                                                     \
            for (int j = 0; j < 5; ++j) {                                         \
                const float4 v = in4[pb_ + off0[j]];                              \
                F[4*j+0] = v.x * m0[j]; F[4*j+1] = v.y * m0[j];                   \
                F[4*j+2] = v.z * m0[j]; F[4*j+3] = v.w * m0[j];                   \
            }                                                                     \
            float ax = 0.f, ay = 0.f, az = 0.f, aw = 0.f;                         \
            _Pragma("unroll")                                                     \
            for (int k = 0; k < KS; ++k) {                                        \
                const float gw_ = g[k];                                           \
                ax += gw_ * F[k + 2]; ay += gw_ * F[k + 3];                       \
                az += gw_ * F[k + 4]; aw += gw_ * F[k + 5];                       \
            }                                                                     \
            wcb[wbase + l] = make_float4(ax, ay, az, aw);                         \
            if (t1act) {                                                          \
                float F2[20];                                                     \
                _Pragma("unroll")                                                 \
                for (int j = 0; j < 5; ++j) {                                     \
                    const float4 v = in4[pb_ + off1[j]];                          \
                    F2[4*j+0] = v.x * m1[j]; F2[4*j+1] = v.y * m1[j];             \
                    F2[4*j+2] = v.z * m1[j]; F2[4*j+3] = v.w * m1[j];             \
                }                                                                 \
                float bx = 0.f, by = 0.f, bz = 0.f, bw = 0.f;                     \
                _Pragma("unroll")                                                 \
                for (int k = 0; k < KS; ++k) {                                    \
                    const float gw_ = g[k];                                       \
                    bx += gw_ * F2[k + 2]; by += gw_ * F2[k + 3];                 \
                    bz += gw_ * F2[k + 4]; bw += gw_ * F2[k + 5];                 \
                }                                                                 \
                wcb[wbase + 64 + l] = make_float4(bx, by, bz, bw);                \
            }                                                                     \
        } else {                                                                  \
            wcb[wbase + l] = z4;                                                  \
            if (t1act) wcb[wbase + 64 + l] = z4;                                  \
        }                                                                         \
        /* WAVE fence: drain DS writes + stop compiler reordering (no s_barrier)*/\
        asm volatile("s_waitcnt lgkmcnt(0)" ::: "memory");                        \
        __builtin_amdgcn_sched_barrier(0);                                        \
        float4 wh = z4;                                                           \
        _Pragma("unroll")                                                         \
        for (int k = 0; k < KS; ++k) {                                            \
            const float4 T = wcb[wbase + l + 2 * k];                              \
            const float gw_ = g[k];                                               \
            wh.x += gw_ * T.x; wh.y += gw_ * T.y;                                 \
            wh.z += gw_ * T.z; wh.w += gw_ * T.w;                                 \
        }                                                                         \
        wd[12 + (OFF)] = wh;                                                      \
        if (s_ >= 2 * RAD) {                                                      \
            const int o_ = d0 + s_ - 2 * RAD;                                     \
            float4 A = z4;                                                        \
            _Pragma("unroll")                                                     \
            for (int j = 0; j < KS; ++j) {                                        \
                const float gw_ = g[j];                                           \
                const float4 v = wd[j + (OFF)];                                   \
                A.x += gw_ * v.x; A.y += gw_ * v.y;                               \
                A.z += gw_ * v.z; A.w += gw_ * v.w;                               \
            }                                                                     \
            out4[outB + o_ * PLANE4] = A;                                         \
        }                                                                         \
    }

#pragma unroll 1
    for (int s2 = 0; s2 < NSTEP; s2 += 2) {
        STEPX(s2, 0)
        STEPX(s2 + 1, 1)
#pragma unroll
        for (int j = 0; j < 12; ++j) wd[j] = wd[j + 2];   // pair shift
    }
#undef STEPX
}

// Fallback: direct 2197-tap depthwise conv (only if ws_size is too small).
__global__ void naive_conv3d_kernel(const float* __restrict__ x, const float* __restrict__ w,
                                    float* __restrict__ out, int total) {
    int n = blockIdx.x * blockDim.x + threadIdx.x;
    if (n >= total) return;
    int wp = n % DIM;
    int h = (n / DIM) % DIM;
    int d = (n / (DIM * DIM)) % DIM;
    int c = n / (DIM * DIM * DIM);
    const float* wc = w + c * KS * KS * KS;
    const float* xc = x + (size_t)c * DIM * DIM * DIM;
    float acc = 0.f;
    for (int kd = 0; kd < KS; ++kd) {
        int dd = d + kd - RAD;
        if (dd < 0 || dd >= DIM) continue;
        for (int kh = 0; kh < KS; ++kh) {
            int hh = h + kh - RAD;
            if (hh < 0 || hh >= DIM) continue;
            for (int kw = 0; kw < KS; ++kw) {
                int ww = wp + kw - RAD;
                if (ww < 0 || ww >= DIM) continue;
                acc += wc[(kd * KS + kh) * KS + kw] * xc[((size_t)dd * DIM + hh) * DIM + ww];
            }
        }
    }
    out[n] = acc;
}

extern "C" void kernel_launch(void* const* d_in, const int* in_sizes, int n_in,
                              void* d_out, int out_size, void* d_ws, size_t ws_size,
                              hipStream_t stream) {
    const float* x = (const float*)d_in[0];
    const float* w = (const float*)d_in[1];
    float* out = (float*)d_out;

    if (ws_size >= 64) {
        float* g1 = (float*)d_ws;
        g1_extract_kernel<<<1, 64, 0, stream>>>(w, g1);
        conv3d_fused<<<GRIDF, NTF, 0, stream>>>(x, out, g1);
    } else {
        const int threads = 256;
        const int blocks = (TOTAL + threads - 1) / threads;
        naive_conv3d_kernel<<<blocks, threads, 0, stream>>>(x, w, out, TOTAL);
    }
}